// Round 1
// baseline (51.539 us; speedup 1.0000x reference)
//
#include <hip/hip_runtime.h>

#define NCLUSTER 512
#define NC 3
#define HW 65536

// One thread per pixel. Distances computed in fp64 (exact to ~1e-16) so the
// argmin is the true argmin; strict '<' keeps the first index on ties,
// matching jnp.argmin semantics.
__global__ __launch_bounds__(256) void kmeans_assign_f64(
    const float* __restrict__ x,   // [4,3,256,256]
    const float* __restrict__ C,   // [512,3]
    int* __restrict__ out,         // [4,65536] int32
    int total)
{
    __shared__ double lc0[NCLUSTER];
    __shared__ double lc1[NCLUSTER];
    __shared__ double lc2[NCLUSTER];
    for (int k = threadIdx.x; k < NCLUSTER; k += blockDim.x) {
        lc0[k] = (double)C[k * NC + 0];
        lc1[k] = (double)C[k * NC + 1];
        lc2[k] = (double)C[k * NC + 2];
    }
    __syncthreads();

    int tid = blockIdx.x * blockDim.x + threadIdx.x;
    if (tid >= total) return;

    int b = tid >> 16;        // batch
    int p = tid & (HW - 1);   // pixel within batch

    const float* xb = x + (size_t)b * NC * HW + p;
    double x0 = (double)xb[0];
    double x1 = (double)xb[HW];
    double x2 = (double)xb[2 * HW];

    double best = 1e300;
    int bestk = 0;
#pragma unroll 4
    for (int k = 0; k < NCLUSTER; ++k) {
        double d0 = x0 - lc0[k];
        double d1 = x1 - lc1[k];
        double d2 = x2 - lc2[k];
        double d = d0 * d0 + d1 * d1 + d2 * d2;
        if (d < best) { best = d; bestk = k; }
    }
    out[tid] = bestk;
}

extern "C" void kernel_launch(void* const* d_in, const int* in_sizes, int n_in,
                              void* d_out, int out_size, void* d_ws, size_t ws_size,
                              hipStream_t stream) {
    const float* x = (const float*)d_in[0];
    const float* C = (const float*)d_in[1];
    int* out = (int*)d_out;

    int total = out_size;  // 4 * 65536 = 262144
    int block = 256;
    int grid = (total + block - 1) / block;
    kmeans_assign_f64<<<grid, block, 0, stream>>>(x, C, out, total);
}